// Round 2
// baseline (24644.963 us; speedup 1.0000x reference)
//
#include <hip/hip_runtime.h>
#include <hip/hip_bf16.h>

typedef __hip_bfloat16 bf16;

#define BATCH 16384
#define DD 32
#define EE 8
#define HH 64
#define TT 10

#define ELEMS_PER_BLOCK 64
#define FPAD 2   // f_lds row = 258 bf16 = 516B = 129 words -> bank stride 1 mod 32 (conflict-free)
#define GPAD 2   // gg_lds row = 66 bf16 = 132B = 33 words  -> bank stride 1 mod 32

__device__ __forceinline__ float b2f(bf16 v) { return __bfloat162float(v); }

// tanh via exp-based form; saturates correctly at +/-inf (no NaN):
// x>>0: e=inf -> 1 - 2*rcp(inf) = 1;  x<<0: e=0 -> 1 - 2*rcp(1) = -1
__device__ __forceinline__ float fast_tanh(float x) {
  float e = __expf(2.f * x);
  return 1.f - 2.f * __builtin_amdgcn_rcpf(e + 1.f);
}

// lane = batch element within block (64), wave = expert (8 waves, 512 threads).
// Expert index made wave-uniform via readfirstlane -> weight reads become
// scalar (SMEM) loads; VALU does only FMAs/tanh.
__global__ __launch_bounds__(512, 2) void ame_ode_kernel(
    const float* __restrict__ x0, const float* __restrict__ tspan,
    const float* __restrict__ W1, const float* __restrict__ b1,
    const float* __restrict__ W2, const float* __restrict__ b2,
    const float* __restrict__ W3, const float* __restrict__ b3,
    const float* __restrict__ Gw1, const float* __restrict__ Gb1,
    const float* __restrict__ Gw2, const float* __restrict__ Gb2,
    float* __restrict__ out)
{
  __shared__ bf16 f_lds[ELEMS_PER_BLOCK][EE * DD + FPAD];   // per-element all-expert f
  __shared__ bf16 gg_lds[ELEMS_PER_BLOCK][HH + GPAD];       // gating hidden

  const int lane = threadIdx.x & 63;
  const int e    = __builtin_amdgcn_readfirstlane(threadIdx.x >> 6);  // wave-uniform expert id
  const int b    = blockIdx.x * ELEMS_PER_BLOCK + lane;

  const float* W1f  = W1 + e * (DD + 1) * HH;
  const float* b1f  = b1 + e * HH;
  const float* W2f  = W2 + e * HH * HH;
  const float* b2fp = b2 + e * HH;
  const float* W3f  = W3 + e * HH * DD;
  const float* b3f  = b3 + e * DD;

  float x[DD];
  #pragma unroll
  for (int d = 0; d < DD; d++) x[d] = x0[b * DD + d];

  if (e == 0) {
    #pragma unroll
    for (int d = 0; d < DD; d++) out[(b * TT + 0) * DD + d] = x[d];
  }

  #pragma unroll 1
  for (int step = 0; step < TT - 1; step++) {
    const float t0 = tspan[step];
    const float t1 = tspan[step + 1];
    const float dt = t1 - t0;

    float ksum[DD];
    float kcur[DD];
    #pragma unroll
    for (int d = 0; d < DD; d++) { ksum[d] = 0.f; kcur[d] = 0.f; }

    #pragma unroll 1
    for (int s = 0; s < 4; s++) {
      const float ci = (s == 0) ? 0.f : ((s == 3) ? 1.f : 0.5f);
      const float wk = (s == 1 || s == 2) ? 2.f : 1.f;
      const float tcur = t0 + ci * dt;

      float xs[DD];
      #pragma unroll
      for (int d = 0; d < DD; d++) xs[d] = __builtin_fmaf(ci * dt, kcur[d], x[d]);

      // ---------------- dyn(tcur, xs) -> kcur ----------------
      // Phase A: this wave's expert: h1 -> h2 -> f
      float h1[HH];
      #pragma unroll
      for (int h = 0; h < HH; h++) h1[h] = b1f[h];
      #pragma unroll
      for (int i = 0; i < DD; i++) {
        const float xi = xs[i];
        const float* w = W1f + i * HH;
        #pragma unroll
        for (int h = 0; h < HH; h++) h1[h] = __builtin_fmaf(xi, w[h], h1[h]);
      }
      {
        const float* w = W1f + DD * HH;   // time row of W1
        #pragma unroll
        for (int h = 0; h < HH; h++) h1[h] = __builtin_fmaf(tcur, w[h], h1[h]);
      }
      #pragma unroll
      for (int h = 0; h < HH; h++) h1[h] = fast_tanh(h1[h]);

      float h2[HH];
      #pragma unroll
      for (int g = 0; g < HH; g++) h2[g] = b2fp[g];
      #pragma unroll
      for (int h = 0; h < HH; h++) {
        const float a = h1[h];
        const float* w = W2f + h * HH;
        #pragma unroll
        for (int g = 0; g < HH; g++) h2[g] = __builtin_fmaf(a, w[g], h2[g]);
      }
      #pragma unroll
      for (int g = 0; g < HH; g++) h2[g] = fast_tanh(h2[g]);

      float f[DD];
      #pragma unroll
      for (int d = 0; d < DD; d++) f[d] = b3f[d];
      #pragma unroll
      for (int g = 0; g < HH; g++) {
        const float a = h2[g];
        const float* w = W3f + g * DD;
        #pragma unroll
        for (int d = 0; d < DD; d++) f[d] = __builtin_fmaf(a, w[d], f[d]);
      }
      #pragma unroll
      for (int d = 0; d < DD; d++) f_lds[lane][e * DD + d] = __float2bfloat16(f[d]);

      __syncthreads();

      // Phase B: dx_init (mean over experts) + this wave's 8 gating hidden units
      float dx[DD];
      #pragma unroll
      for (int d = 0; d < DD; d++) {
        float acc = 0.f;
        #pragma unroll
        for (int ee = 0; ee < EE; ee++) acc += b2f(f_lds[lane][ee * DD + d]);
        dx[d] = acc * (1.f / EE);
      }
      #pragma unroll
      for (int hh = 0; hh < HH / EE; hh++) {
        const int h = e * (HH / EE) + hh;
        float acc = Gb1[h];
        #pragma unroll
        for (int i = 0; i < DD; i++) acc = __builtin_fmaf(xs[i], Gw1[i * HH + h], acc);
        #pragma unroll
        for (int i = 0; i < DD; i++) acc = __builtin_fmaf(dx[i], Gw1[(DD + i) * HH + h], acc);
        gg_lds[lane][h] = __float2bfloat16(fast_tanh(acc));
      }
      __syncthreads();

      // Phase C (redundant per wave): logits -> softmax -> weighted sum
      float lg[EE];
      #pragma unroll
      for (int j = 0; j < EE; j++) lg[j] = Gb2[j];
      #pragma unroll
      for (int h = 0; h < HH; h++) {
        const float a = b2f(gg_lds[lane][h]);
        #pragma unroll
        for (int j = 0; j < EE; j++) lg[j] = __builtin_fmaf(a, Gw2[h * EE + j], lg[j]);
      }
      float m = lg[0];
      #pragma unroll
      for (int j = 1; j < EE; j++) m = fmaxf(m, lg[j]);
      float wsm[EE];
      float ssum = 0.f;
      #pragma unroll
      for (int j = 0; j < EE; j++) { wsm[j] = __expf(lg[j] - m); ssum += wsm[j]; }
      const float inv = __builtin_amdgcn_rcpf(ssum);

      #pragma unroll
      for (int d = 0; d < DD; d++) kcur[d] = 0.f;
      #pragma unroll
      for (int j = 0; j < EE; j++) {
        const float wgt = wsm[j] * inv;
        #pragma unroll
        for (int d = 0; d < DD; d++)
          kcur[d] = __builtin_fmaf(wgt, b2f(f_lds[lane][j * DD + d]), kcur[d]);
      }
      __syncthreads();   // f_lds/gg_lds reads done before next stage overwrites

      #pragma unroll
      for (int d = 0; d < DD; d++) ksum[d] += wk * kcur[d];
    } // stages

    #pragma unroll
    for (int d = 0; d < DD; d++) x[d] = __builtin_fmaf(dt * (1.f / 6.f), ksum[d], x[d]);

    if (e == 0) {
      #pragma unroll
      for (int d = 0; d < DD; d++)
        out[(b * TT + step + 1) * DD + d] = x[d];
    }
  } // steps
}

extern "C" void kernel_launch(void* const* d_in, const int* in_sizes, int n_in,
                              void* d_out, int out_size, void* d_ws, size_t ws_size,
                              hipStream_t stream)
{
  const float* x0    = (const float*)d_in[0];
  const float* tspan = (const float*)d_in[1];
  const float* W1  = (const float*)d_in[2];
  const float* b1  = (const float*)d_in[3];
  const float* W2  = (const float*)d_in[4];
  const float* b2  = (const float*)d_in[5];
  const float* W3  = (const float*)d_in[6];
  const float* b3  = (const float*)d_in[7];
  const float* Gw1 = (const float*)d_in[8];
  const float* Gb1 = (const float*)d_in[9];
  const float* Gw2 = (const float*)d_in[10];
  const float* Gb2 = (const float*)d_in[11];

  ame_ode_kernel<<<BATCH / ELEMS_PER_BLOCK, 512, 0, stream>>>(
      x0, tspan, W1, b1, W2, b2, W3, b3, Gw1, Gb1, Gw2, Gb2, (float*)d_out);
}

// Round 3
// 5131.527 us; speedup vs baseline: 4.8027x; 4.8027x over previous
//
#include <hip/hip_runtime.h>
#include <hip/hip_bf16.h>

typedef __hip_bfloat16 bf16;

#define DD 32
#define EE 8
#define HH 64
#define TT 10
#define BATCH 16384
#define EPB 64          // batch elements per block (one per lane)

__device__ __forceinline__ float fast_tanh(float x) {
  // 1 - 2/(e^{2x}+1); saturates to +/-1 at +/-inf, no NaN
  float e = __expf(2.f * x);
  return 1.f - 2.f * __builtin_amdgcn_rcpf(e + 1.f);
}

__device__ __forceinline__ unsigned pack2(float a, float b) {
  unsigned ua = (unsigned)__bfloat16_as_ushort(__float2bfloat16(a));
  unsigned ub = (unsigned)__bfloat16_as_ushort(__float2bfloat16(b));
  return ua | (ub << 16);
}
__device__ __forceinline__ float unp_lo(unsigned p) { return __uint_as_float(p << 16); }
__device__ __forceinline__ float unp_hi(unsigned p) { return __uint_as_float(p & 0xffff0000u); }

// lane = batch element (64/block), wave = expert (8 waves).
// h1/h2 streamed in chunks of 8 -> peak live regs ~115 (no spills).
// Per-element ODE state lives in LDS; phase C distributed by dim (wave e owns dims 4e..4e+3).
__global__ __launch_bounds__(512) void ame_ode_kernel(
    const float* __restrict__ x0, const float* __restrict__ tspan,
    const float* __restrict__ W1, const float* __restrict__ b1,
    const float* __restrict__ W2, const float* __restrict__ b2,
    const float* __restrict__ W3, const float* __restrict__ b3,
    const float* __restrict__ Gw1, const float* __restrict__ Gb1,
    const float* __restrict__ Gw2, const float* __restrict__ Gb2,
    float* __restrict__ out)
{
  __shared__ float    xst_s[EPB][DD + 1];     // current x        (stride 33 w == 1 mod 32)
  __shared__ float    xacc_s[EPB][DD + 1];    // x + (dt/6)*sum(wk*k)
  __shared__ float    xs_s[EPB][DD + 1];      // stage input x
  __shared__ unsigned f_s[EPB][EE * 16 + 1];  // all-expert f, bf16x2 packed (stride 129 w)
  __shared__ float    lg_s[EPB][EE + 1];      // gating logits accumulator

  const int lane = threadIdx.x & 63;
  const int e    = __builtin_amdgcn_readfirstlane(threadIdx.x >> 6);  // wave-uniform expert/dim-group
  const int b    = blockIdx.x * EPB + lane;

  const float* W1f = W1 + e * (DD + 1) * HH;
  const float* b1f = b1 + e * HH;
  const float* W2f = W2 + e * HH * HH;
  const float* b2f = b2 + e * HH;
  const float* W3f = W3 + e * HH * DD;
  const float* b3f = b3 + e * DD;

  // ---- init: wave e loads/stores its 4 dims for all 64 elements ----
  {
    const float4 v = *(const float4*)(x0 + b * DD + e * 4);
    xst_s[lane][e * 4 + 0] = v.x;  xst_s[lane][e * 4 + 1] = v.y;
    xst_s[lane][e * 4 + 2] = v.z;  xst_s[lane][e * 4 + 3] = v.w;
    xacc_s[lane][e * 4 + 0] = v.x; xacc_s[lane][e * 4 + 1] = v.y;
    xacc_s[lane][e * 4 + 2] = v.z; xacc_s[lane][e * 4 + 3] = v.w;
    xs_s[lane][e * 4 + 0] = v.x;   xs_s[lane][e * 4 + 1] = v.y;
    xs_s[lane][e * 4 + 2] = v.z;   xs_s[lane][e * 4 + 3] = v.w;
    *(float4*)(out + (b * TT + 0) * DD + e * 4) = v;
  }
  __syncthreads();

  #pragma unroll 1
  for (int step = 0; step < TT - 1; step++) {
    const float t0 = tspan[step];
    const float t1 = tspan[step + 1];
    const float dt = t1 - t0;

    #pragma unroll 1
    for (int s = 0; s < 4; s++) {
      const float tcur = (s == 0) ? t0 : ((s == 3) ? t1 : t0 + 0.5f * dt);

      // ---------- Phase A: this wave's expert MLP, streamed ----------
      if (e == 0) {               // re-init logits accumulator for this stage
        #pragma unroll
        for (int j = 0; j < EE; j++) lg_s[lane][j] = Gb2[j];
      }

      float h2a[HH];
      #pragma unroll
      for (int g = 0; g < HH; g++) h2a[g] = b2f[g];

      {
        float xs[DD];
        #pragma unroll
        for (int d = 0; d < DD; d++) xs[d] = xs_s[lane][d];

        #pragma unroll 1
        for (int c = 0; c < 8; c++) {          // h1 in chunks of 8
          float h1c[8];
          #pragma unroll
          for (int j = 0; j < 8; j++) h1c[j] = b1f[c * 8 + j];
          #pragma unroll
          for (int i = 0; i < DD; i++) {
            const float xi = xs[i];
            #pragma unroll
            for (int j = 0; j < 8; j++)
              h1c[j] = __builtin_fmaf(xi, W1f[i * HH + c * 8 + j], h1c[j]);
          }
          #pragma unroll
          for (int j = 0; j < 8; j++)
            h1c[j] = __builtin_fmaf(tcur, W1f[DD * HH + c * 8 + j], h1c[j]);
          #pragma unroll
          for (int j = 0; j < 8; j++) h1c[j] = fast_tanh(h1c[j]);
          #pragma unroll
          for (int j = 0; j < 8; j++) {        // rank-8 update of h2
            const float a = h1c[j];
            const float* w = W2f + (c * 8 + j) * HH;
            #pragma unroll
            for (int g = 0; g < HH; g++) h2a[g] = __builtin_fmaf(a, w[g], h2a[g]);
          }
        }
      } // xs regs die here

      float fv[DD];
      #pragma unroll
      for (int d = 0; d < DD; d++) fv[d] = b3f[d];
      #pragma unroll 1
      for (int c = 0; c < 8; c++) {            // h2 -> f, streamed
        float hc[8];
        #pragma unroll
        for (int j = 0; j < 8; j++) hc[j] = fast_tanh(h2a[c * 8 + j]);
        #pragma unroll
        for (int j = 0; j < 8; j++) {
          const float a = hc[j];
          const float* w = W3f + (c * 8 + j) * DD;
          #pragma unroll
          for (int d = 0; d < DD; d++) fv[d] = __builtin_fmaf(a, w[d], fv[d]);
        }
      }
      #pragma unroll
      for (int k = 0; k < 16; k++)
        f_s[lane][e * 16 + k] = pack2(fv[2 * k], fv[2 * k + 1]);

      __syncthreads();

      // ---------- Phase B: dx mean + 8 gate hiddens -> logit partials ----------
      {
        float dx[DD];
        #pragma unroll
        for (int d = 0; d < DD; d++) dx[d] = 0.f;
        #pragma unroll
        for (int ee2 = 0; ee2 < EE; ee2++) {
          #pragma unroll
          for (int k = 0; k < 16; k++) {
            const unsigned p = f_s[lane][ee2 * 16 + k];
            dx[2 * k]     += unp_lo(p);
            dx[2 * k + 1] += unp_hi(p);
          }
        }
        #pragma unroll
        for (int d = 0; d < DD; d++) dx[d] *= 0.125f;

        float xs2[DD];
        #pragma unroll
        for (int d = 0; d < DD; d++) xs2[d] = xs_s[lane][d];

        float lgp[EE];
        #pragma unroll
        for (int j = 0; j < EE; j++) lgp[j] = 0.f;
        #pragma unroll 1
        for (int hh = 0; hh < 8; hh++) {
          const int h = e * 8 + hh;
          float acc = Gb1[h];
          #pragma unroll
          for (int i = 0; i < DD; i++) acc = __builtin_fmaf(xs2[i], Gw1[i * HH + h], acc);
          #pragma unroll
          for (int i = 0; i < DD; i++) acc = __builtin_fmaf(dx[i], Gw1[(DD + i) * HH + h], acc);
          const float gv = fast_tanh(acc);
          #pragma unroll
          for (int j = 0; j < EE; j++) lgp[j] = __builtin_fmaf(gv, Gw2[h * EE + j], lgp[j]);
        }
        #pragma unroll
        for (int j = 0; j < EE; j++) atomicAdd(&lg_s[lane][j], lgp[j]);
      }
      __syncthreads();

      // ---------- Phase C: softmax + weighted sum + state update (dims 4e..4e+3) ----------
      {
        float lg[EE];
        #pragma unroll
        for (int j = 0; j < EE; j++) lg[j] = lg_s[lane][j];
        float m = lg[0];
        #pragma unroll
        for (int j = 1; j < EE; j++) m = fmaxf(m, lg[j]);
        float w8[EE], ssum = 0.f;
        #pragma unroll
        for (int j = 0; j < EE; j++) { w8[j] = __expf(lg[j] - m); ssum += w8[j]; }
        const float inv = __builtin_amdgcn_rcpf(ssum);

        float kc[4] = {0.f, 0.f, 0.f, 0.f};
        #pragma unroll
        for (int j = 0; j < EE; j++) {
          const float wgt = w8[j] * inv;
          const unsigned p0 = f_s[lane][j * 16 + 2 * e];
          const unsigned p1 = f_s[lane][j * 16 + 2 * e + 1];
          kc[0] = __builtin_fmaf(wgt, unp_lo(p0), kc[0]);
          kc[1] = __builtin_fmaf(wgt, unp_hi(p0), kc[1]);
          kc[2] = __builtin_fmaf(wgt, unp_lo(p1), kc[2]);
          kc[3] = __builtin_fmaf(wgt, unp_hi(p1), kc[3]);
        }

        const float wk = (s == 1 || s == 2) ? 2.f : 1.f;
        const float ak = (dt * (1.f / 6.f)) * wk;
        float xa[4];
        #pragma unroll
        for (int q = 0; q < 4; q++) {
          xa[q] = __builtin_fmaf(ak, kc[q], xacc_s[lane][e * 4 + q]);
          xacc_s[lane][e * 4 + q] = xa[q];
        }
        if (s < 3) {
          const float cn = (s == 2) ? dt : 0.5f * dt;
          #pragma unroll
          for (int q = 0; q < 4; q++)
            xs_s[lane][e * 4 + q] = __builtin_fmaf(cn, kc[q], xst_s[lane][e * 4 + q]);
        } else {
          #pragma unroll
          for (int q = 0; q < 4; q++) {
            xst_s[lane][e * 4 + q] = xa[q];
            xs_s[lane][e * 4 + q]  = xa[q];
          }
          float4 o; o.x = xa[0]; o.y = xa[1]; o.z = xa[2]; o.w = xa[3];
          *(float4*)(out + (b * TT + step + 1) * DD + e * 4) = o;
        }
      }
      __syncthreads();
    } // stages
  } // steps
}

extern "C" void kernel_launch(void* const* d_in, const int* in_sizes, int n_in,
                              void* d_out, int out_size, void* d_ws, size_t ws_size,
                              hipStream_t stream)
{
  const float* x0    = (const float*)d_in[0];
  const float* tspan = (const float*)d_in[1];
  const float* W1  = (const float*)d_in[2];
  const float* b1  = (const float*)d_in[3];
  const float* W2  = (const float*)d_in[4];
  const float* b2  = (const float*)d_in[5];
  const float* W3  = (const float*)d_in[6];
  const float* b3  = (const float*)d_in[7];
  const float* Gw1 = (const float*)d_in[8];
  const float* Gb1 = (const float*)d_in[9];
  const float* Gw2 = (const float*)d_in[10];
  const float* Gb2 = (const float*)d_in[11];

  ame_ode_kernel<<<BATCH / EPB, 512, 0, stream>>>(
      x0, tspan, W1, b1, W2, b2, W3, b3, Gw1, Gb1, Gw2, Gb2, (float*)d_out);
}

// Round 4
// 3538.301 us; speedup vs baseline: 6.9652x; 1.4503x over previous
//
#include <hip/hip_runtime.h>
#include <hip/hip_bf16.h>

typedef __hip_bfloat16 bf16;

#define DD 32
#define EE 8
#define HH 64
#define TT 10
#define BATCH 16384
#define EPB 64          // batch elements per block (one per lane)

__device__ __forceinline__ float fast_tanh(float x) {
  // 1 - 2/(e^{2x}+1); saturates to +/-1 at +/-inf, no NaN
  float e = __expf(2.f * x);
  return 1.f - 2.f * __builtin_amdgcn_rcpf(e + 1.f);
}

__device__ __forceinline__ unsigned pack2(float a, float b) {
  unsigned ua = (unsigned)__bfloat16_as_ushort(__float2bfloat16(a));
  unsigned ub = (unsigned)__bfloat16_as_ushort(__float2bfloat16(b));
  return ua | (ub << 16);
}
__device__ __forceinline__ float unp_lo(unsigned p) { return __uint_as_float(p << 16); }
__device__ __forceinline__ float unp_hi(unsigned p) { return __uint_as_float(p & 0xffff0000u); }

// lane = batch element (64/block), wave = expert (8 waves).
// RULE: private arrays are only indexed by compile-time constants (fully
// unrolled consumer loops) -- dynamic indexing demotes the array to scratch
// (round-3 lesson: 10.5 GB of scratch writebacks from h2a[c*8+j]).
__global__ __launch_bounds__(512, 2) void ame_ode_kernel(
    const float* __restrict__ x0, const float* __restrict__ tspan,
    const float* __restrict__ W1, const float* __restrict__ b1,
    const float* __restrict__ W2, const float* __restrict__ b2,
    const float* __restrict__ W3, const float* __restrict__ b3,
    const float* __restrict__ Gw1, const float* __restrict__ Gb1,
    const float* __restrict__ Gw2, const float* __restrict__ Gb2,
    float* __restrict__ out)
{
  __shared__ float    xst_s[EPB][DD + 1];     // current x   (stride 33 w == 1 mod 32: conflict-free)
  __shared__ float    xacc_s[EPB][DD + 1];    // x + (dt/6)*sum(wk*k)
  __shared__ float    xs_s[EPB][DD + 1];      // stage input x
  __shared__ unsigned f_s[EPB][EE * 16 + 1];  // all-expert f, bf16x2 packed (stride 129 w)
  __shared__ float    lg_s[EPB][EE + 1];      // gating logits accumulator

  const int lane = threadIdx.x & 63;
  const int e    = __builtin_amdgcn_readfirstlane(threadIdx.x >> 6);  // wave-uniform expert id
  const int b    = blockIdx.x * EPB + lane;

  const float* W1f = W1 + e * (DD + 1) * HH;
  const float* b1f = b1 + e * HH;
  const float* W2f = W2 + e * HH * HH;
  const float* b2f = b2 + e * HH;
  const float* W3f = W3 + e * HH * DD;
  const float* b3f = b3 + e * DD;

  // ---- init: wave e loads/stores its 4 dims for all 64 elements ----
  {
    const float4 v = *(const float4*)(x0 + b * DD + e * 4);
    xst_s[lane][e * 4 + 0] = v.x;  xst_s[lane][e * 4 + 1] = v.y;
    xst_s[lane][e * 4 + 2] = v.z;  xst_s[lane][e * 4 + 3] = v.w;
    xacc_s[lane][e * 4 + 0] = v.x; xacc_s[lane][e * 4 + 1] = v.y;
    xacc_s[lane][e * 4 + 2] = v.z; xacc_s[lane][e * 4 + 3] = v.w;
    xs_s[lane][e * 4 + 0] = v.x;   xs_s[lane][e * 4 + 1] = v.y;
    xs_s[lane][e * 4 + 2] = v.z;   xs_s[lane][e * 4 + 3] = v.w;
    *(float4*)(out + (b * TT + 0) * DD + e * 4) = v;
  }
  __syncthreads();

  #pragma unroll 1
  for (int step = 0; step < TT - 1; step++) {
    const float t0 = tspan[step];
    const float t1 = tspan[step + 1];
    const float dt = t1 - t0;

    #pragma unroll 1
    for (int s = 0; s < 4; s++) {
      const float tcur = (s == 0) ? t0 : ((s == 3) ? t1 : t0 + 0.5f * dt);

      if (e == 0) {               // re-init logits accumulator for this stage
        #pragma unroll
        for (int j = 0; j < EE; j++) lg_s[lane][j] = Gb2[j];
      }

      // ---------- Phase A1+A2: h1 (chunks of 8, streamed) -> h2 accumulator ----------
      float h2a[HH];
      #pragma unroll
      for (int g = 0; g < HH; g++) h2a[g] = b2f[g];

      {
        // volatile: force per-chunk LDS reads (LICM would hoist 32 regs)
        const volatile float* xsl = &xs_s[lane][0];
        #pragma unroll 1
        for (int c = 0; c < 8; c++) {
          float h1c[8];
          #pragma unroll
          for (int j = 0; j < 8; j++)
            h1c[j] = __builtin_fmaf(tcur, W1f[DD * HH + c * 8 + j], b1f[c * 8 + j]);
          #pragma unroll
          for (int i = 0; i < DD; i++) {
            const float xi = xsl[i];
            #pragma unroll
            for (int j = 0; j < 8; j++)
              h1c[j] = __builtin_fmaf(xi, W1f[i * HH + c * 8 + j], h1c[j]);
          }
          #pragma unroll
          for (int j = 0; j < 8; j++) h1c[j] = fast_tanh(h1c[j]);
          #pragma unroll
          for (int j = 0; j < 8; j++) {        // rank-8 update of h2
            const float a = h1c[j];
            const float* w = W2f + (c * 8 + j) * HH;
            #pragma unroll
            for (int g = 0; g < HH; g++) h2a[g] = __builtin_fmaf(a, w[g], h2a[g]);
          }
        }
      }

      // ---------- Phase A3: tanh(h2) packed bf16 -> f (all indices static) ----------
      unsigned th[HH / 2];
      #pragma unroll
      for (int k = 0; k < HH / 2; k++)
        th[k] = pack2(fast_tanh(h2a[2 * k]), fast_tanh(h2a[2 * k + 1]));

      float fv[DD];
      #pragma unroll
      for (int d = 0; d < DD; d++) fv[d] = b3f[d];
      #pragma unroll
      for (int k = 0; k < HH / 2; k++) {
        const float lo = unp_lo(th[k]);
        const float hi = unp_hi(th[k]);
        const float* w0 = W3f + (2 * k) * DD;
        const float* w1 = W3f + (2 * k + 1) * DD;
        #pragma unroll
        for (int d = 0; d < DD; d++)
          fv[d] = __builtin_fmaf(lo, w0[d], __builtin_fmaf(hi, w1[d], fv[d]));
      }
      #pragma unroll
      for (int k = 0; k < 16; k++)
        f_s[lane][e * 16 + k] = pack2(fv[2 * k], fv[2 * k + 1]);

      __syncthreads();

      // ---------- Phase B: gate hiddens (8 per wave) without dx/xs arrays ----------
      {
        float hacc[8];
        #pragma unroll
        for (int hh = 0; hh < 8; hh++) hacc[hh] = Gb1[e * 8 + hh];

        // x part of concat(x, dx)
        #pragma unroll 1
        for (int i4 = 0; i4 < 8; i4++) {
          float xv[4];
          #pragma unroll
          for (int q = 0; q < 4; q++) xv[q] = xs_s[lane][i4 * 4 + q];
          #pragma unroll
          for (int q = 0; q < 4; q++) {
            const float xi = xv[q];
            const float* w = Gw1 + (i4 * 4 + q) * HH + e * 8;
            #pragma unroll
            for (int hh = 0; hh < 8; hh++) hacc[hh] = __builtin_fmaf(xi, w[hh], hacc[hh]);
          }
        }
        // dx part: mean over experts computed on the fly, never stored
        #pragma unroll 1
        for (int k = 0; k < 16; k++) {
          float dlo = 0.f, dhi = 0.f;
          #pragma unroll
          for (int e2 = 0; e2 < EE; e2++) {
            const unsigned p = f_s[lane][e2 * 16 + k];
            dlo += unp_lo(p); dhi += unp_hi(p);
          }
          dlo *= 0.125f; dhi *= 0.125f;
          const float* wlo = Gw1 + (DD + 2 * k) * HH + e * 8;
          const float* whi = Gw1 + (DD + 2 * k + 1) * HH + e * 8;
          #pragma unroll
          for (int hh = 0; hh < 8; hh++)
            hacc[hh] = __builtin_fmaf(dlo, wlo[hh], __builtin_fmaf(dhi, whi[hh], hacc[hh]));
        }

        float lgp[EE];
        #pragma unroll
        for (int j = 0; j < EE; j++) lgp[j] = 0.f;
        #pragma unroll
        for (int hh = 0; hh < 8; hh++) {
          const float gv = fast_tanh(hacc[hh]);
          const float* w = Gw2 + (e * 8 + hh) * EE;
          #pragma unroll
          for (int j = 0; j < EE; j++) lgp[j] = __builtin_fmaf(gv, w[j], lgp[j]);
        }
        #pragma unroll
        for (int j = 0; j < EE; j++) atomicAdd(&lg_s[lane][j], lgp[j]);
      }
      __syncthreads();

      // ---------- Phase C: softmax + weighted sum + state update (dims 4e..4e+3) ----------
      {
        float lg[EE];
        #pragma unroll
        for (int j = 0; j < EE; j++) lg[j] = lg_s[lane][j];
        float m = lg[0];
        #pragma unroll
        for (int j = 1; j < EE; j++) m = fmaxf(m, lg[j]);
        float w8[EE], ssum = 0.f;
        #pragma unroll
        for (int j = 0; j < EE; j++) { w8[j] = __expf(lg[j] - m); ssum += w8[j]; }
        const float inv = __builtin_amdgcn_rcpf(ssum);

        float kc[4] = {0.f, 0.f, 0.f, 0.f};
        #pragma unroll
        for (int j = 0; j < EE; j++) {
          const float wgt = w8[j] * inv;
          const unsigned p0 = f_s[lane][j * 16 + 2 * e];
          const unsigned p1 = f_s[lane][j * 16 + 2 * e + 1];
          kc[0] = __builtin_fmaf(wgt, unp_lo(p0), kc[0]);
          kc[1] = __builtin_fmaf(wgt, unp_hi(p0), kc[1]);
          kc[2] = __builtin_fmaf(wgt, unp_lo(p1), kc[2]);
          kc[3] = __builtin_fmaf(wgt, unp_hi(p1), kc[3]);
        }

        const float wk = (s == 1 || s == 2) ? 2.f : 1.f;
        const float ak = (dt * (1.f / 6.f)) * wk;
        float xa[4];
        #pragma unroll
        for (int q = 0; q < 4; q++) {
          xa[q] = __builtin_fmaf(ak, kc[q], xacc_s[lane][e * 4 + q]);
          xacc_s[lane][e * 4 + q] = xa[q];
        }
        if (s < 3) {
          const float cn = (s == 2) ? dt : 0.5f * dt;
          #pragma unroll
          for (int q = 0; q < 4; q++)
            xs_s[lane][e * 4 + q] = __builtin_fmaf(cn, kc[q], xst_s[lane][e * 4 + q]);
        } else {
          #pragma unroll
          for (int q = 0; q < 4; q++) {
            xst_s[lane][e * 4 + q] = xa[q];
            xs_s[lane][e * 4 + q]  = xa[q];
          }
          float4 o; o.x = xa[0]; o.y = xa[1]; o.z = xa[2]; o.w = xa[3];
          *(float4*)(out + (b * TT + step + 1) * DD + e * 4) = o;
        }
      }
      __syncthreads();
    } // stages
  } // steps
}

extern "C" void kernel_launch(void* const* d_in, const int* in_sizes, int n_in,
                              void* d_out, int out_size, void* d_ws, size_t ws_size,
                              hipStream_t stream)
{
  const float* x0    = (const float*)d_in[0];
  const float* tspan = (const float*)d_in[1];
  const float* W1  = (const float*)d_in[2];
  const float* b1  = (const float*)d_in[3];
  const float* W2  = (const float*)d_in[4];
  const float* b2  = (const float*)d_in[5];
  const float* W3  = (const float*)d_in[6];
  const float* b3  = (const float*)d_in[7];
  const float* Gw1 = (const float*)d_in[8];
  const float* Gb1 = (const float*)d_in[9];
  const float* Gw2 = (const float*)d_in[10];
  const float* Gb2 = (const float*)d_in[11];

  ame_ode_kernel<<<BATCH / EPB, 512, 0, stream>>>(
      x0, tspan, W1, b1, W2, b2, W3, b3, Gw1, Gb1, Gw2, Gb2, (float*)d_out);
}

// Round 5
// 658.470 us; speedup vs baseline: 37.4276x; 5.3735x over previous
//
#include <hip/hip_runtime.h>
#include <hip/hip_bf16.h>

typedef unsigned int u32;
typedef unsigned short u16;
typedef __attribute__((ext_vector_type(8))) short short8;   // 8 bf16 (4 VGPRs) MFMA A/B frag
typedef __attribute__((ext_vector_type(4))) float f32x4;    // MFMA C/D frag
typedef __attribute__((ext_vector_type(4))) u32 u32x4;

#define DD 32
#define EE 8
#define HH 64
#define TT 10
#define BATCH 16384
#define EPB 64          // batch elements per block

__device__ __forceinline__ float fast_tanh(float x) {
  // 1 - 2/(e^{2x}+1); saturates to +/-1 at +/-inf, no NaN
  float e = __expf(2.f * x);
  return 1.f - 2.f * __builtin_amdgcn_rcpf(e + 1.f);
}
__device__ __forceinline__ u16 f2b(float v) {
  return __bfloat16_as_ushort(__float2bfloat16(v));
}
__device__ __forceinline__ u32 pack2(float a, float b) {
  return (u32)f2b(a) | ((u32)f2b(b) << 16);
}
__device__ __forceinline__ float unp_lo(u32 p) { return __uint_as_float(p << 16); }
__device__ __forceinline__ float unp_hi(u32 p) { return __uint_as_float(p & 0xffff0000u); }
__device__ __forceinline__ short8 lds_frag(const u32* p) {
  u32x4 w = *(const u32x4*)p;               // ds_read_b128 (callers guarantee 16B align)
  return __builtin_bit_cast(short8, w);
}

// wave = expert (8 waves, 512 thr), 64 batch elements per block.
// Phase A: per-wave MFMA GEMMs (16x16x32 bf16), weights preloaded as B-frags in regs.
//   C/D layout: col=lane&15, row=(lane>>4)*4+reg.  A layout: A[m=lane&15][k=(lane>>4)*8+j].
// Biases + W1 t-row folded into MFMA C-init (col-only -> broadcast over 4 acc regs).
// Layer transform (C-frag -> A-frag) via per-wave LDS scratch, no barrier (in-wave).
__global__ __launch_bounds__(512, 2) void ame_ode_kernel(
    const float* __restrict__ x0, const float* __restrict__ tspan,
    const float* __restrict__ W1, const float* __restrict__ b1,
    const float* __restrict__ W2, const float* __restrict__ b2,
    const float* __restrict__ W3, const float* __restrict__ b3,
    const float* __restrict__ Gw1, const float* __restrict__ Gb1,
    const float* __restrict__ Gw2, const float* __restrict__ Gb2,
    float* __restrict__ out)
{
  // stride 20 u32 (80B): row*80 % 16 == 0 -> b128-aligned; banks perfectly balanced
  __shared__ __align__(16) u32 xsb[EPB][20];       // xs, bf16x2 packed       (5120 B)
  __shared__ __align__(16) u32 fs[EPB][145];       // [elem][e*16 + d/2]; cols 128..143 = dx (37120 B)
  __shared__ __align__(16) float lg[EPB][8];       // gating logits           (2048 B)
  __shared__ __align__(16) u32 hs[EE][16][36];     // per-wave h transform scratch (18432 B)
  // total 62720 B

  const int tid  = threadIdx.x;
  const int lane = tid & 63;
  const int l15  = lane & 15;
  const int quad = lane >> 4;
  const int e    = __builtin_amdgcn_readfirstlane(tid >> 6);   // wave-uniform expert id
  const int b    = blockIdx.x * EPB + lane;

  const float* W1f = W1 + e * (DD + 1) * HH;
  const float* b1f = b1 + e * HH;
  const float* W2f = W2 + e * HH * HH;
  const float* b2f = b2 + e * HH;
  const float* W3f = W3 + e * HH * DD;
  const float* b3f = b3 + e * DD;

  // ---- one-time weight preload into B-fragments: B[k=(quad*8+j)][n=l15+16*nt] ----
  short8 bw1[4], bw2[2][4], bw3[2][2];
  #pragma unroll
  for (int nt = 0; nt < 4; nt++)
    #pragma unroll
    for (int j = 0; j < 8; j++)
      bw1[nt][j] = (short)f2b(W1f[(quad * 8 + j) * HH + nt * 16 + l15]);
  #pragma unroll
  for (int ks = 0; ks < 2; ks++)
    #pragma unroll
    for (int nt = 0; nt < 4; nt++)
      #pragma unroll
      for (int j = 0; j < 8; j++)
        bw2[ks][nt][j] = (short)f2b(W2f[(ks * 32 + quad * 8 + j) * HH + nt * 16 + l15]);
  #pragma unroll
  for (int ks = 0; ks < 2; ks++)
    #pragma unroll
    for (int dt = 0; dt < 2; dt++)
      #pragma unroll
      for (int j = 0; j < 8; j++)
        bw3[ks][dt][j] = (short)f2b(W3f[(ks * 32 + quad * 8 + j) * DD + dt * 16 + l15]);

  // per-lane C-init components (depend on col = nt*16+l15 only)
  float c1b[4], c1t[4], c2b[4], c3b[2];
  #pragma unroll
  for (int nt = 0; nt < 4; nt++) {
    c1b[nt] = b1f[nt * 16 + l15];
    c1t[nt] = W1f[DD * HH + nt * 16 + l15];   // t-row of W1
    c2b[nt] = b2f[nt * 16 + l15];
  }
  #pragma unroll
  for (int dt = 0; dt < 2; dt++) c3b[dt] = b3f[dt * 16 + l15];

  // ---- state init: wave e owns dims 4e..4e+3 of elem=lane ----
  float xst[4], xacc[4];
  {
    const float4 v = *(const float4*)(x0 + b * DD + e * 4);
    xst[0] = v.x; xst[1] = v.y; xst[2] = v.z; xst[3] = v.w;
    xacc[0] = v.x; xacc[1] = v.y; xacc[2] = v.z; xacc[3] = v.w;
    xsb[lane][2 * e]     = pack2(v.x, v.y);
    xsb[lane][2 * e + 1] = pack2(v.z, v.w);
    *(float4*)(out + (b * TT + 0) * DD + e * 4) = v;
  }
  __syncthreads();

  u16* const hw16 = (u16*)&hs[e][0][0];   // this wave's scratch, ushort view (row stride 72 u16)
  u16* const fw16 = (u16*)&fs[0][0];      // fs ushort view (row stride 290 u16)

  #pragma unroll 1
  for (int step = 0; step < TT - 1; step++) {
    const float t0 = tspan[step];
    const float t1 = tspan[step + 1];
    const float dt = t1 - t0;

    #pragma unroll 1
    for (int s = 0; s < 4; s++) {
      const float tcur = (s == 0) ? t0 : ((s == 3) ? t1 : t0 + 0.5f * dt);

      // ================= Phase A: expert MLP via MFMA =================
      if (e == 0) {    // logits accumulator init (uniform scalars)
        float4 g0; g0.x = Gb2[0]; g0.y = Gb2[1]; g0.z = Gb2[2]; g0.w = Gb2[3];
        float4 g1; g1.x = Gb2[4]; g1.y = Gb2[5]; g1.z = Gb2[6]; g1.w = Gb2[7];
        *(float4*)(&lg[lane][0]) = g0;
        *(float4*)(&lg[lane][4]) = g1;
      }

      #pragma unroll 1
      for (int mt = 0; mt < 4; mt++) {
        // ---- L1: h1 = X @ W1 (K=32; t-term & bias in C-init) ----
        const short8 a1 = lds_frag(&xsb[mt * 16 + l15][quad * 4]);
        f32x4 h1a[4];
        #pragma unroll
        for (int nt = 0; nt < 4; nt++) {
          const float iv = __builtin_fmaf(tcur, c1t[nt], c1b[nt]);
          f32x4 c; c[0] = iv; c[1] = iv; c[2] = iv; c[3] = iv;
          h1a[nt] = __builtin_amdgcn_mfma_f32_16x16x32_bf16(a1, bw1[nt], c, 0, 0, 0);
        }
        // tanh -> bf16 -> scratch (row = quad*4+r, col = nt*16+l15)
        #pragma unroll
        for (int nt = 0; nt < 4; nt++)
          #pragma unroll
          for (int r = 0; r < 4; r++)
            hw16[(quad * 4 + r) * 72 + nt * 16 + l15] = f2b(fast_tanh(h1a[nt][r]));

        // ---- L2: h2 = tanh(h1) @ W2 (K=64) ----
        f32x4 h2a[4];
        #pragma unroll
        for (int nt = 0; nt < 4; nt++) {
          f32x4 c; c[0] = c2b[nt]; c[1] = c2b[nt]; c[2] = c2b[nt]; c[3] = c2b[nt];
          h2a[nt] = c;
        }
        #pragma unroll
        for (int ks = 0; ks < 2; ks++) {
          const short8 a2 = lds_frag(&hs[e][l15][ks * 16 + quad * 4]);
          #pragma unroll
          for (int nt = 0; nt < 4; nt++)
            h2a[nt] = __builtin_amdgcn_mfma_f32_16x16x32_bf16(a2, bw2[ks][nt], h2a[nt], 0, 0, 0);
        }
        #pragma unroll
        for (int nt = 0; nt < 4; nt++)
          #pragma unroll
          for (int r = 0; r < 4; r++)
            hw16[(quad * 4 + r) * 72 + nt * 16 + l15] = f2b(fast_tanh(h2a[nt][r]));

        // ---- L3: f = tanh(h2) @ W3 (K=64, N=32) ----
        f32x4 fa[2];
        #pragma unroll
        for (int dt2 = 0; dt2 < 2; dt2++) {
          f32x4 c; c[0] = c3b[dt2]; c[1] = c3b[dt2]; c[2] = c3b[dt2]; c[3] = c3b[dt2];
          fa[dt2] = c;
        }
        #pragma unroll
        for (int ks = 0; ks < 2; ks++) {
          const short8 a3 = lds_frag(&hs[e][l15][ks * 16 + quad * 4]);
          #pragma unroll
          for (int dt2 = 0; dt2 < 2; dt2++)
            fa[dt2] = __builtin_amdgcn_mfma_f32_16x16x32_bf16(a3, bw3[ks][dt2], fa[dt2], 0, 0, 0);
        }
        // f[m = mt*16+quad*4+r][d = dt2*16+l15] -> fs (bf16)
        #pragma unroll
        for (int dt2 = 0; dt2 < 2; dt2++)
          #pragma unroll
          for (int r = 0; r < 4; r++)
            fw16[(mt * 16 + quad * 4 + r) * 290 + e * 32 + dt2 * 16 + l15] = f2b(fa[dt2][r]);
      } // mt
      __syncthreads();   // barrier A: fs f-cols + lg init visible

      // ===== Phase B1: dx = mean_e f  (wave e -> dims 4e..4e+3, elem=lane) =====
      {
        float s0 = 0.f, s1 = 0.f, s2 = 0.f, s3 = 0.f;
        #pragma unroll
        for (int j = 0; j < EE; j++) {
          const u32 p0 = fs[lane][j * 16 + 2 * e];
          const u32 p1 = fs[lane][j * 16 + 2 * e + 1];
          s0 += unp_lo(p0); s1 += unp_hi(p0);
          s2 += unp_lo(p1); s3 += unp_hi(p1);
        }
        fs[lane][128 + 2 * e]     = pack2(s0 * 0.125f, s1 * 0.125f);
        fs[lane][128 + 2 * e + 1] = pack2(s2 * 0.125f, s3 * 0.125f);
      }
      __syncthreads();   // barrier B1: dx visible

      // ===== Phase B2: gate hiddens 8e..8e+7 (elem=lane), logits via LDS atomics =====
      {
        float hacc[8];
        #pragma unroll
        for (int hh = 0; hh < 8; hh++) hacc[hh] = Gb1[e * 8 + hh];

        #pragma unroll
        for (int c = 0; c < 4; c++) {                    // x part (bf16 xs)
          const u32x4 w = *(const u32x4*)(&xsb[lane][c * 4]);
          #pragma unroll
          for (int p = 0; p < 4; p++) {
            const float xa = unp_lo(w[p]);
            const float xb = unp_hi(w[p]);
            const int i = c * 8 + 2 * p;
            const float* g0 = Gw1 + i * HH + e * 8;
            const float* g1 = Gw1 + (i + 1) * HH + e * 8;
            #pragma unroll
            for (int hh = 0; hh < 8; hh++)
              hacc[hh] = __builtin_fmaf(xa, g0[hh], __builtin_fmaf(xb, g1[hh], hacc[hh]));
          }
        }
        #pragma unroll
        for (int c = 0; c < 16; c++) {                   // dx part
          const u32 p = fs[lane][128 + c];
          const float da = unp_lo(p);
          const float db = unp_hi(p);
          const float* g0 = Gw1 + (DD + 2 * c) * HH + e * 8;
          const float* g1 = Gw1 + (DD + 2 * c + 1) * HH + e * 8;
          #pragma unroll
          for (int hh = 0; hh < 8; hh++)
            hacc[hh] = __builtin_fmaf(da, g0[hh], __builtin_fmaf(db, g1[hh], hacc[hh]));
        }
        float lgp[EE];
        #pragma unroll
        for (int j = 0; j < EE; j++) lgp[j] = 0.f;
        #pragma unroll
        for (int hh = 0; hh < 8; hh++) {
          const float gv = fast_tanh(hacc[hh]);
          const float* w = Gw2 + (e * 8 + hh) * EE;
          #pragma unroll
          for (int j = 0; j < EE; j++) lgp[j] = __builtin_fmaf(gv, w[j], lgp[j]);
        }
        #pragma unroll
        for (int j = 0; j < EE; j++) atomicAdd(&lg[lane][j], lgp[j]);
      }
      __syncthreads();   // barrier B2: logits complete

      // ===== Phase C: softmax + weighted sum + RK4 state update (dims 4e..4e+3) =====
      {
        float la[8];
        const float4 v0 = *(const float4*)(&lg[lane][0]);
        const float4 v1 = *(const float4*)(&lg[lane][4]);
        la[0] = v0.x; la[1] = v0.y; la[2] = v0.z; la[3] = v0.w;
        la[4] = v1.x; la[5] = v1.y; la[6] = v1.z; la[7] = v1.w;
        float m = la[0];
        #pragma unroll
        for (int j = 1; j < EE; j++) m = fmaxf(m, la[j]);
        float w8[EE], ss = 0.f;
        #pragma unroll
        for (int j = 0; j < EE; j++) { w8[j] = __expf(la[j] - m); ss += w8[j]; }
        const float inv = __builtin_amdgcn_rcpf(ss);

        float kc[4] = {0.f, 0.f, 0.f, 0.f};
        #pragma unroll
        for (int j = 0; j < EE; j++) {
          const float wg = w8[j] * inv;
          const u32 p0 = fs[lane][j * 16 + 2 * e];
          const u32 p1 = fs[lane][j * 16 + 2 * e + 1];
          kc[0] = __builtin_fmaf(wg, unp_lo(p0), kc[0]);
          kc[1] = __builtin_fmaf(wg, unp_hi(p0), kc[1]);
          kc[2] = __builtin_fmaf(wg, unp_lo(p1), kc[2]);
          kc[3] = __builtin_fmaf(wg, unp_hi(p1), kc[3]);
        }

        const float wk = (s == 1 || s == 2) ? 2.f : 1.f;
        const float ak = dt * (1.f / 6.f) * wk;
        #pragma unroll
        for (int q = 0; q < 4; q++) xacc[q] = __builtin_fmaf(ak, kc[q], xacc[q]);

        float xn[4];
        if (s < 3) {
          const float cn = (s == 2) ? dt : 0.5f * dt;
          #pragma unroll
          for (int q = 0; q < 4; q++) xn[q] = __builtin_fmaf(cn, kc[q], xst[q]);
        } else {
          #pragma unroll
          for (int q = 0; q < 4; q++) { xst[q] = xacc[q]; xn[q] = xacc[q]; }
          float4 o; o.x = xn[0]; o.y = xn[1]; o.z = xn[2]; o.w = xn[3];
          *(float4*)(out + (b * TT + step + 1) * DD + e * 4) = o;
        }
        xsb[lane][2 * e]     = pack2(xn[0], xn[1]);
        xsb[lane][2 * e + 1] = pack2(xn[2], xn[3]);
      }
      __syncthreads();   // end of stage
    } // stages
  } // steps
}

extern "C" void kernel_launch(void* const* d_in, const int* in_sizes, int n_in,
                              void* d_out, int out_size, void* d_ws, size_t ws_size,
                              hipStream_t stream)
{
  const float* x0    = (const float*)d_in[0];
  const float* tspan = (const float*)d_in[1];
  const float* W1  = (const float*)d_in[2];
  const float* b1  = (const float*)d_in[3];
  const float* W2  = (const float*)d_in[4];
  const float* b2  = (const float*)d_in[5];
  const float* W3  = (const float*)d_in[6];
  const float* b3  = (const float*)d_in[7];
  const float* Gw1 = (const float*)d_in[8];
  const float* Gb1 = (const float*)d_in[9];
  const float* Gw2 = (const float*)d_in[10];
  const float* Gb2 = (const float*)d_in[11];

  ame_ode_kernel<<<BATCH / EPB, 512, 0, stream>>>(
      x0, tspan, W1, b1, W2, b2, W3, b3, Gw1, Gb1, Gw2, Gb2, (float*)d_out);
}